// Round 1
// 388.499 us; speedup vs baseline: 1.0856x; 1.0856x over previous
//
#include <hip/hip_runtime.h>
#include <stdint.h>

// out[(b,m),n] = (sum_k x_q[(b,m),k] * w[n,k]) * sx[(b,m)] * ws[n] + bias[n]
// pass 1: int32 -> packed int8 (coalesced 16B load -> 4B store per lane)
// pass 2: 256x256-tile i8 MFMA GEMM (16x16x64), 8 waves, 4-deep LDS ring
//         (128 KB), counted vmcnt(8) pipeline (never drains in main loop),
//         raw s_barrier (1/K-tile), setprio around MFMA clusters, 16B-chunk
//         XOR swizzle on LDS layout (pre-swizzled global source).
#define MROWS 8192
#define K_DIM 4096
#define N_DIM 4096
#define BM 256
#define BN 256
#define BK 64                 // bytes of K per tile
#define KT (K_DIM / BK)       // 64 K-tiles
#define ABYTES (BM * BK)      // 16 KB per matrix per tile
#define TBYTES (2 * ABYTES)   // 32 KB per ring slot (A+B)

#define X_ELEMS (MROWS * K_DIM)
#define W_ELEMS (N_DIM * K_DIM)

typedef __attribute__((ext_vector_type(4))) int   int4v;
typedef __attribute__((ext_vector_type(4))) float float4v;

#define GLOAD_LDS16(gptr, lptr)                                                   \
    __builtin_amdgcn_global_load_lds((const __attribute__((address_space(1))) void*)(gptr), \
                                     (__attribute__((address_space(3))) void*)(lptr), 16, 0, 0)

// ---- pass 1: int32 -> packed int8, fully coalesced --------------------------
__device__ __forceinline__ int pack4(int4v v) {
    return (int)((unsigned)(v[0] & 0xFF)
               | ((unsigned)(v[1] & 0xFF) << 8)
               | ((unsigned)(v[2] & 0xFF) << 16)
               | ((unsigned)(v[3] & 0xFF) << 24));
}

__global__ __launch_bounds__(256) void pack_i32_to_i8(
    const int4v* __restrict__ src, int* __restrict__ dst, int n4)
{
    int i = blockIdx.x * blockDim.x + threadIdx.x;
    if (i < n4) dst[i] = pack4(src[i]);
}

// ---- pass 2: i8 GEMM + dequant epilogue -------------------------------------
// LDS swizzle (per 64B row, 4 x 16B chunks): chunk c of row r stored at slot
// (c + (r>>1)) & 3, realized by pre-swizzling the per-lane GLOBAL source so
// the hardware's linear lane*16 LDS placement lands the permutation.
__global__ __launch_bounds__(512, 2) void i8gemm_dq_kernel(
    const int8_t* __restrict__ xq,   // (8192, 4096) packed i8
    const float*  __restrict__ sx,   // (8192,)
    const int8_t* __restrict__ wt,   // (4096, 4096) packed i8 (row = n)
    const float*  __restrict__ ws,   // (4096,)
    const float*  __restrict__ bias, // (4096,)
    float*        __restrict__ out)  // (8192, 4096) f32
{
    __shared__ __align__(16) int8_t lds8[4 * TBYTES];   // 128 KB ring

    const int tid  = threadIdx.x;
    const int wave = tid >> 6;
    const int lane = tid & 63;
    const int wr   = wave >> 2;   // 0..1 : 128-row half of the 256-row tile
    const int wcn  = wave & 3;    // 0..3 : 64-col quarter of the 256-col tile

    // XCD-aware swizzle: 512 blocks, 8 XCDs, 64 contiguous wgs per XCD
    const int bid = blockIdx.x;
    const int wg  = (bid & 7) * 64 + (bid >> 3);
    const int ct  = wg & 15;          // 16 col tiles
    const int rt  = wg >> 4;          // 32 row tiles

    // ---- staging addressing: lane covers (row = wave*16 + lane>>2, chunk = lane&3)
    // global chunk fetched = (slot - (row>>1)) & 3; (row>>1)&3 == (lane>>3)&3.
    const int srow = wave * 16 + (lane >> 2);
    const int scol = (((lane & 3) - ((lane >> 3) & 3)) & 3) * 16;
    const int8_t* gA0 = xq + (size_t)(rt * BM + srow) * K_DIM + scol;       // rows 0..127
    const int8_t* gA1 = gA0 + (size_t)128 * K_DIM;                          // rows 128..255
    const int8_t* gB0 = wt + (size_t)(ct * BN + srow) * K_DIM + scol;
    const int8_t* gB1 = gB0 + (size_t)128 * K_DIM;
    const int dA0 = wave * 1024;            // LDS dest offsets (wave-uniform)
    const int dA1 = 8192 + wave * 1024;
    const int dB0 = ABYTES + wave * 1024;
    const int dB1 = ABYTES + 8192 + wave * 1024;

    // ---- fragment read addressing (same XOR-swizzle on the read side) ----
    const int mrow = lane & 15;
    const int kswz = (((lane >> 4) + (mrow >> 1)) & 3) * 16;
    const int aoff = (wr * 128 + mrow) * BK + kswz;            // + i*1024
    const int boff = ABYTES + (wcn * 64 + mrow) * BK + kswz;   // + j*1024

    int4v acc[8][4] = {};   // 8x4 of 16x16 int32 accumulators per wave

    // prologue: stage tiles 0..2 into slots 0..2 -> 12 loads/wave in flight
    #pragma unroll
    for (int u = 0; u < 3; ++u) {
        const size_t ko = (size_t)u * BK;
        int8_t* bb = lds8 + u * TBYTES;
        GLOAD_LDS16(gA0 + ko, bb + dA0);
        GLOAD_LDS16(gA1 + ko, bb + dA1);
        GLOAD_LDS16(gB0 + ko, bb + dB0);
        GLOAD_LDS16(gB1 + ko, bb + dB1);
    }

    #pragma unroll 4
    for (int t = 0; t < KT; ++t) {
        const int  buf = t & 3;
        const int  nb  = (t + 3) & 3;           // ring slot last read at t-1: dead
        const int  u   = (t + 3) & (KT - 1);    // wraps at the tail (data unused)
        const size_t ko = (size_t)u * BK;
        const int8_t* base = lds8 + buf * TBYTES;
        int8_t* nbb = lds8 + nb * TBYTES;

        // land this tile's 4 loads (oldest), keep 8 in flight; then barrier so
        // every wave's staging of this tile is visible to every other wave.
        asm volatile("s_waitcnt vmcnt(8)" ::: "memory");
        __builtin_amdgcn_s_barrier();
        __builtin_amdgcn_sched_barrier(0);

        // phase 0: rows wr*128 + 0..63
        int4v a[4], b[4];
        #pragma unroll
        for (int i = 0; i < 4; ++i) a[i] = *(const int4v*)(base + aoff + i * 1024);
        #pragma unroll
        for (int j = 0; j < 4; ++j) b[j] = *(const int4v*)(base + boff + j * 1024);
        GLOAD_LDS16(gA0 + ko, nbb + dA0);   // prefetch A of tile t+3
        GLOAD_LDS16(gA1 + ko, nbb + dA1);

        __builtin_amdgcn_s_setprio(1);
        #pragma unroll
        for (int i = 0; i < 4; ++i)
            #pragma unroll
            for (int j = 0; j < 4; ++j)
                acc[i][j] = __builtin_amdgcn_mfma_i32_16x16x64_i8(a[i], b[j], acc[i][j], 0, 0, 0);
        __builtin_amdgcn_s_setprio(0);

        // phase 1: rows wr*128 + 64..127 (B frags reused)
        int4v a2[4];
        #pragma unroll
        for (int i = 0; i < 4; ++i) a2[i] = *(const int4v*)(base + aoff + (4 + i) * 1024);
        GLOAD_LDS16(gB0 + ko, nbb + dB0);   // prefetch B of tile t+3
        GLOAD_LDS16(gB1 + ko, nbb + dB1);

        __builtin_amdgcn_s_setprio(1);
        #pragma unroll
        for (int i = 0; i < 4; ++i)
            #pragma unroll
            for (int j = 0; j < 4; ++j)
                acc[4 + i][j] = __builtin_amdgcn_mfma_i32_16x16x64_i8(a2[i], b[j], acc[4 + i][j], 0, 0, 0);
        __builtin_amdgcn_s_setprio(0);
    }

    // drain LDS-DMA before workgroup can end (ring slots die with the WG)
    asm volatile("s_waitcnt vmcnt(0)" ::: "memory");

    // ---- epilogue: C/D layout col=lane&15, row=(lane>>4)*4+reg ----
    const int row_base = rt * BM + wr * 128;
    const int col_base = ct * BN + wcn * 64;
    const int crow = (lane >> 4) * 4;
    const int ccol = lane & 15;

    float wsc[4], bsc[4];
    #pragma unroll
    for (int j = 0; j < 4; ++j) {
        const int c = col_base + j * 16 + ccol;
        wsc[j] = ws[c];
        bsc[j] = bias[c];
    }

    #pragma unroll
    for (int i = 0; i < 8; ++i) {
        const int r0 = row_base + i * 16 + crow;
        const float4v sx4 = *(const float4v*)(sx + r0);
        #pragma unroll
        for (int j = 0; j < 4; ++j) {
            const int c = col_base + j * 16 + ccol;
            float* o = out + (size_t)r0 * N_DIM + c;
            #pragma unroll
            for (int r = 0; r < 4; ++r)
                o[(size_t)r * N_DIM] = (float)acc[i][j][r] * sx4[r] * wsc[j] + bsc[j];
        }
    }
}

extern "C" void kernel_launch(void* const* d_in, const int* in_sizes, int n_in,
                              void* d_out, int out_size, void* d_ws, size_t ws_size,
                              hipStream_t stream) {
    const int*   xq32 = (const int*)d_in[0];
    const float* sx   = (const float*)d_in[1];
    const int*   wt32 = (const int*)d_in[2];
    const float* ws   = (const float*)d_in[3];
    const float* bias = (const float*)d_in[4];
    float* out = (float*)d_out;

    int8_t* xq8 = (int8_t*)d_ws;
    int8_t* wt8 = xq8 + (size_t)X_ELEMS;

    {
        int n4x = X_ELEMS / 4;   // 8388608 -> 32768 blocks
        int n4w = W_ELEMS / 4;   // 4194304 -> 16384 blocks
        pack_i32_to_i8<<<n4x / 256, 256, 0, stream>>>((const int4v*)xq32, (int*)xq8, n4x);
        pack_i32_to_i8<<<n4w / 256, 256, 0, stream>>>((const int4v*)wt32, (int*)wt8, n4w);
    }

    dim3 grid((MROWS / BM) * (N_DIM / BN));  // 512 blocks
    i8gemm_dq_kernel<<<grid, 512, 0, stream>>>(xq8, sx, wt8, ws, bias, out);
}